// Round 1
// baseline (445.624 us; speedup 1.0000x reference)
//
#include <hip/hip_runtime.h>

// ForwardBackwardImputer: reference collapses to pure forward-fill:
//   out[b,l,:] = x[b, F(b,l), :],  F(b,l) = cummax_{l'<=l}( valid(l') ? l' : 0 )
//   valid(l) <=> NOT all |x[b,l,d]| <= 1e-6  (isclose to 0 with atol=1e-6, rtol*0)
// (The reference's "backward fill" is provably idx_bwd==0 everywhere, and on
//  still_missing rows x_fwd==x[b,0,:]==x_bwd, so it is a no-op.)

constexpr int Bn = 256;
constexpr int Ln = 2048;
constexpr int Dn = 128;          // 128 floats = 512 B per row
constexpr float A_TOL = 1e-6f;

// ---------------------------------------------------------------------------
// Kernel A: per row (32 lanes, float4 each = 512 B):
//   - validity via ballot
//   - write idx[row] = valid ? l : 0
//   - copy-through to out for valid rows and for l==0 (F(0)==0 always)
// ---------------------------------------------------------------------------
__global__ __launch_bounds__(256) void
kernelA(const float* __restrict__ x, float* __restrict__ out,
        int* __restrict__ idx) {
    const int gid    = blockIdx.x * blockDim.x + threadIdx.x;
    const int row    = gid >> 5;          // 32 lanes per row
    const int lane32 = gid & 31;
    if (row >= Bn * Ln) return;

    const size_t off = (size_t)row * 32 + lane32;   // in float4 units
    const float4 v = ((const float4*)x)[off];

    const bool near0 = (__builtin_fabsf(v.x) <= A_TOL) &
                       (__builtin_fabsf(v.y) <= A_TOL) &
                       (__builtin_fabsf(v.z) <= A_TOL) &
                       (__builtin_fabsf(v.w) <= A_TOL);
    const unsigned long long bal = __ballot(near0);
    const int half = (threadIdx.x & 63) >> 5;       // which 32-lane group of the wave
    const unsigned int mine = (unsigned int)(bal >> (half * 32));
    const bool missing = (mine == 0xffffffffu);     // all 128 features ~0

    const int l = row & (Ln - 1);
    if (!missing || l == 0) {
        ((float4*)out)[off] = v;
    }
    if (lane32 == 0) {
        idx[row] = missing ? 0 : l;
    }
}

// ---------------------------------------------------------------------------
// Kernel B: in-place inclusive max-scan of idx along L, one block per batch b.
// 256 threads x 8 elements. Hillis-Steele over thread partials.
// ---------------------------------------------------------------------------
__global__ __launch_bounds__(256) void
kernelB(int* __restrict__ idx) {
    __shared__ int s[256];
    const int b = blockIdx.x;
    const int t = threadIdx.x;
    int* base = idx + (size_t)b * Ln + t * 8;

    int4 a0 = ((const int4*)base)[0];
    int4 a1 = ((const int4*)base)[1];
    int v[8] = {a0.x, a0.y, a0.z, a0.w, a1.x, a1.y, a1.z, a1.w};

    int m = 0;
    #pragma unroll
    for (int i = 0; i < 8; ++i) m = max(m, v[i]);
    s[t] = m;
    __syncthreads();

    #pragma unroll
    for (int offd = 1; offd < 256; offd <<= 1) {
        int mine  = s[t];
        int other = (t >= offd) ? s[t - offd] : 0;
        __syncthreads();
        s[t] = max(mine, other);
        __syncthreads();
    }

    int run = (t > 0) ? s[t - 1] : 0;
    int o[8];
    #pragma unroll
    for (int i = 0; i < 8; ++i) { run = max(run, v[i]); o[i] = run; }

    ((int4*)base)[0] = make_int4(o[0], o[1], o[2], o[3]);
    ((int4*)base)[1] = make_int4(o[4], o[5], o[6], o[7]);
}

// ---------------------------------------------------------------------------
// Kernel C: rows with F != l (missing rows, l>0): out[b,l,:] = x[b,F,:]
// ---------------------------------------------------------------------------
__global__ __launch_bounds__(256) void
kernelC(const float* __restrict__ x, float* __restrict__ out,
        const int* __restrict__ idx) {
    const int gid    = blockIdx.x * blockDim.x + threadIdx.x;
    const int row    = gid >> 5;
    const int lane32 = gid & 31;
    if (row >= Bn * Ln) return;

    const int l = row & (Ln - 1);
    const int F = idx[row];
    if (F == l) return;

    const int b      = row >> 11;               // Ln = 2048 = 2^11
    const size_t src = ((size_t)((b << 11) + F)) * 32 + lane32;
    const size_t dst = (size_t)row * 32 + lane32;
    ((float4*)out)[dst] = ((const float4*)x)[src];
}

extern "C" void kernel_launch(void* const* d_in, const int* in_sizes, int n_in,
                              void* d_out, int out_size, void* d_ws, size_t ws_size,
                              hipStream_t stream) {
    const float* x = (const float*)d_in[0];
    float* out     = (float*)d_out;
    int* idx       = (int*)d_ws;                // needs Bn*Ln*4 = 2 MB

    const int totalRowThreads = Bn * Ln * 32;   // 16,777,216
    const int blk = 256;
    const int gridA = totalRowThreads / blk;    // 65536

    kernelA<<<gridA, blk, 0, stream>>>(x, out, idx);
    kernelB<<<Bn, blk, 0, stream>>>(idx);
    kernelC<<<gridA, blk, 0, stream>>>(x, out, idx);
}